// Round 2
// baseline (1339.349 us; speedup 1.0000x reference)
//
#include <hip/hip_runtime.h>
#include <stdint.h>

// Problem constants
#define H_    16
#define N_    2048
#define DIM_  1024
#define DH_   64
#define NN_   2
#define J_    2050     // N + NNULL
#define B_    2
#define M_    4096     // B * N

typedef unsigned short u16;
typedef short bf16x8 __attribute__((ext_vector_type(8)));
typedef float f32x4 __attribute__((ext_vector_type(4)));

__device__ __forceinline__ float b2f(u16 u) {
  union { unsigned int i; float f; } v; v.i = ((unsigned int)u) << 16; return v.f;
}
__device__ __forceinline__ u16 f2b(float f) {
  union { float f; unsigned int i; } v; v.f = f;
  unsigned int r = v.i + 0x7fffu + ((v.i >> 16) & 1u);   // RNE
  return (u16)(r >> 16);
}
__device__ __forceinline__ float lo2f(unsigned int u) {
  union { unsigned int i; float f; } v; v.i = u << 16; return v.f;
}
__device__ __forceinline__ float hi2f(unsigned int u) {
  union { unsigned int i; float f; } v; v.i = u & 0xffff0000u; return v.f;
}
__device__ __forceinline__ void unp8(const uint4 u, float* d) {
  d[0] = lo2f(u.x); d[1] = hi2f(u.x); d[2] = lo2f(u.y); d[3] = hi2f(u.y);
  d[4] = lo2f(u.z); d[5] = hi2f(u.z); d[6] = lo2f(u.w); d[7] = hi2f(u.w);
}

// ---------------- transpose + cast (fp32 R x C -> bf16 C x R) ----------------
__global__ __launch_bounds__(256) void ktranspose_cast(const float* __restrict__ in,
                                                       u16* __restrict__ out, int R, int C) {
  __shared__ float tile[32][33];
  int tx = threadIdx.x & 31, ty = threadIdx.x >> 5;   // 32 x 8
  int c0 = blockIdx.x * 32, r0 = blockIdx.y * 32;
  #pragma unroll
  for (int i = 0; i < 32; i += 8)
    tile[ty + i][tx] = in[(size_t)(r0 + ty + i) * C + c0 + tx];
  __syncthreads();
  #pragma unroll
  for (int i = 0; i < 32; i += 8)
    out[(size_t)(c0 + ty + i) * R + r0 + tx] = f2b(tile[tx][ty + i]);
}

// ---------------- cast fp32 -> bf16, 8 elems/thread ----------------
__global__ __launch_bounds__(256) void castx_k(const float* __restrict__ in,
                                               u16* __restrict__ out) {
  int i = blockIdx.x * 256 + threadIdx.x;
  float4 a = ((const float4*)in)[2 * i];
  float4 b = ((const float4*)in)[2 * i + 1];
  uint4 o;
  o.x = (unsigned)f2b(a.x) | ((unsigned)f2b(a.y) << 16);
  o.y = (unsigned)f2b(a.z) | ((unsigned)f2b(a.w) << 16);
  o.z = (unsigned)f2b(b.x) | ((unsigned)f2b(b.y) << 16);
  o.w = (unsigned)f2b(b.z) | ((unsigned)f2b(b.w) << 16);
  ((uint4*)out)[i] = o;
}

// ---------------- LayerNorm (fp32 in, bf16 out), row of 1024 ----------------
__global__ __launch_bounds__(256) void lnorm_k(const float* __restrict__ x,
                                               const float* __restrict__ g,
                                               const float* __restrict__ bb,
                                               u16* __restrict__ xn) {
  int row = blockIdx.x;
  int t = threadIdx.x;
  float4 rw = *(const float4*)(x + (size_t)row * DIM_ + t * 4);
  float v0 = rw.x, v1 = rw.y, v2 = rw.z, v3 = rw.w;
  float s = v0 + v1 + v2 + v3;
  float ss = v0 * v0 + v1 * v1 + v2 * v2 + v3 * v3;
  #pragma unroll
  for (int o = 32; o; o >>= 1) { s += __shfl_xor(s, o, 64); ss += __shfl_xor(ss, o, 64); }
  __shared__ float red[8];
  int lane = t & 63, w = t >> 6;
  if (lane == 0) { red[w] = s; red[4 + w] = ss; }
  __syncthreads();
  float S = red[0] + red[1] + red[2] + red[3];
  float SS = red[4] + red[5] + red[6] + red[7];
  float mu = S * (1.0f / DIM_);
  float var = SS * (1.0f / DIM_) - mu * mu;
  float rs = rsqrtf(var + 1e-5f);
  float4 gv = *(const float4*)(g + t * 4);
  float4 bv = *(const float4*)(bb + t * 4);
  uint2 ow;
  ow.x = (unsigned)f2b((v0 - mu) * rs * gv.x + bv.x) |
         ((unsigned)f2b((v1 - mu) * rs * gv.y + bv.y) << 16);
  ow.y = (unsigned)f2b((v2 - mu) * rs * gv.z + bv.z) |
         ((unsigned)f2b((v3 - mu) * rs * gv.w + bv.w) << 16);
  *(uint2*)(xn + (size_t)row * DIM_ + t * 4) = ow;
}

// ---------------- MFMA GEMM: C[MxNc] = A[MxK] * BT[NcxK]^T ----------------
// 64x64 block tile, 4 waves x (16m x 64n), K-step 32, bf16 in / fp32 acc.
template <bool F32OUT>
__global__ __launch_bounds__(256) void gemm_bt(const u16* __restrict__ A,
                                               const u16* __restrict__ BT,
                                               void* __restrict__ Cv,
                                               int M, int Nc, int K) {
  __shared__ u16 As[64][40];   // stride 40 -> 80B rows: 16B-aligned, 2-way banks only
  __shared__ u16 Bs[64][40];
  int tid = threadIdx.x;
  int wv = tid >> 6, lane = tid & 63;
  int row0 = blockIdx.y * 64, col0 = blockIdx.x * 64;
  f32x4 acc[4] = {};
  int sr = tid >> 2;            // 0..63
  int sk = (tid & 3) * 8;       // 0,8,16,24
  const u16* Ag = A + (size_t)(row0 + sr) * K + sk;
  const u16* Bg = BT + (size_t)(col0 + sr) * K + sk;
  int fm = lane & 15;
  int fk = (lane >> 4) * 8;
  for (int k0 = 0; k0 < K; k0 += 32) {
    *(uint4*)(&As[sr][sk]) = *(const uint4*)(Ag + k0);
    *(uint4*)(&Bs[sr][sk]) = *(const uint4*)(Bg + k0);
    __syncthreads();
    bf16x8 af = *(const bf16x8*)(&As[wv * 16 + fm][fk]);
    #pragma unroll
    for (int nt = 0; nt < 4; nt++) {
      bf16x8 bfr = *(const bf16x8*)(&Bs[nt * 16 + fm][fk]);
      acc[nt] = __builtin_amdgcn_mfma_f32_16x16x32_bf16(af, bfr, acc[nt], 0, 0, 0);
    }
    __syncthreads();
  }
  // C/D layout: col = lane&15, row = (lane>>4)*4 + reg   [m89-verified]
  int cn = lane & 15, cr = (lane >> 4) * 4;
  #pragma unroll
  for (int nt = 0; nt < 4; nt++) {
    #pragma unroll
    for (int r = 0; r < 4; r++) {
      int m = row0 + wv * 16 + cr + r;
      int n = col0 + nt * 16 + cn;
      if (F32OUT) ((float*)Cv)[(size_t)m * Nc + n] = acc[nt][r];
      else        ((u16*)Cv)[(size_t)m * Nc + n] = f2b(acc[nt][r]);
    }
  }
}

// ---------------- Q l2norm + scale, relayout to (b,h,n,d) ----------------
__global__ __launch_bounds__(256) void qnorm_k(const u16* __restrict__ Qraw,
                                               const float* __restrict__ qs,
                                               u16* __restrict__ Qn) {
  int wid = blockIdx.x * 4 + (threadIdx.x >> 6);
  int lane = threadIdx.x & 63;
  int r = wid >> 4, h = wid & 15;
  float v = b2f(Qraw[(size_t)r * 1024 + h * 64 + lane]);
  float ss = v * v;
  #pragma unroll
  for (int o = 32; o; o >>= 1) ss += __shfl_xor(ss, o, 64);
  float dn = fmaxf(sqrtf(ss), 1e-12f);
  float res = v / dn * qs[lane];
  int b = r >> 11, n = r & 2047;
  Qn[(((size_t)(b * H_ + h)) * N_ + n) * 64 + lane] = f2b(res);
}

// ---------------- K l2norm+scale & V copy, relayout to (b,h,j,d), j offset NN ----------------
__global__ __launch_bounds__(256) void kvprep_k(const u16* __restrict__ KVraw,
                                                const float* __restrict__ ks,
                                                u16* __restrict__ Kb, u16* __restrict__ Vb) {
  int wid = blockIdx.x * 4 + (threadIdx.x >> 6);
  int lane = threadIdx.x & 63;
  int r = wid >> 4, h = wid & 15;
  float kv = b2f(KVraw[(size_t)r * 2048 + h * 64 + lane]);
  float ss = kv * kv;
  #pragma unroll
  for (int o = 32; o; o >>= 1) ss += __shfl_xor(ss, o, 64);
  float dn = fmaxf(sqrtf(ss), 1e-12f);
  float res = kv / dn * ks[lane];
  int b = r >> 11, n = r & 2047;
  size_t o = (((size_t)(b * H_ + h)) * J_ + (n + NN_)) * 64 + lane;
  Kb[o] = f2b(res);
  Vb[o] = KVraw[(size_t)r * 2048 + 1024 + h * 64 + lane];  // bf16 passthrough
}

// ---------------- null KV: k l2norm+scale, v copy; j in [0,NN) ----------------
__global__ __launch_bounds__(256) void nullprep_k(const float* __restrict__ nkv,
                                                  const float* __restrict__ ks,
                                                  u16* __restrict__ Kb, u16* __restrict__ Vb) {
  int w = threadIdx.x >> 6, lane = threadIdx.x & 63;
  for (int t = w; t < B_ * H_ * NN_; t += 4) {
    int b = t >> 5, h = (t >> 1) & 15, i = t & 1;
    // null_kv (h, 2*nn, dh) reshaped (h, nn, 2, dh): k = [h][2i+0], v = [h][2i+1]
    float kv = nkv[(size_t)(h * 4 + 2 * i) * 64 + lane];
    float ss = kv * kv;
    #pragma unroll
    for (int o = 32; o; o >>= 1) ss += __shfl_xor(ss, o, 64);
    float dn = fmaxf(sqrtf(ss), 1e-12f);
    size_t o = (((size_t)(b * H_ + h)) * J_ + i) * 64 + lane;
    Kb[o] = f2b(kv / dn * ks[lane]);
    Vb[o] = f2b(nkv[(size_t)(h * 4 + 2 * i + 1) * 64 + lane]);
  }
}

// ---------------- attention: causal + ALiBi + 2 null cols, fixed-cap softmax ----------------
// block = 256 threads: qi = tid&63 (query row), g = tid>>6 (key phase, j%4==g)
// Scores bounded above by Mb = 8*max_d|qs_d*ks_d| (bias<=0, Cauchy-Schwarz) ->
// p = exp(s-Mb) in (0,1]; no online rescale; cross-phase merge is a plain sum.
__global__ __launch_bounds__(256) void attn_k(const u16* __restrict__ Qn,
                                              const u16* __restrict__ Kb,
                                              const u16* __restrict__ Vb,
                                              const float* __restrict__ qs,
                                              const float* __restrict__ ks,
                                              u16* __restrict__ AO) {
  __shared__ float smem[2 * 64 * 68 + 256];
  float* Ks = smem;                 // [64][68] fp32
  float* Vs = smem + 64 * 68;       // [64][68]
  float* lbuf = smem + 2 * 64 * 68; // [4][64]
  int tid = threadIdx.x;
  int qi = tid & 63, g = tid >> 6;
  int bh = blockIdx.y;
  int h = bh & 15, b = bh >> 4;
  int q0 = blockIdx.x * 64;
  int myq = q0 + qi;
  float slope = exp2f(-0.5f * (float)(h + 1));
  // score upper bound
  float prod = fabsf(qs[qi] * ks[qi]);
  #pragma unroll
  for (int o = 32; o; o >>= 1) prod = fmaxf(prod, __shfl_xor(prod, o, 64));
  float Mb = 8.0f * prod;
  // q row into registers
  float qreg[64];
  const u16* qp = Qn + ((size_t)bh * N_ + myq) * 64;
  #pragma unroll
  for (int i8 = 0; i8 < 8; i8++) unp8(*(const uint4*)(qp + i8 * 8), &qreg[i8 * 8]);
  float oreg[64];
  #pragma unroll
  for (int d = 0; d < 64; d++) oreg[d] = 0.0f;
  float l = 0.0f;
  int sj = tid >> 2, sd = (tid & 3) * 16;
  int nch = (q0 + 65) / 64 + 1;
  for (int c = 0; c < nch; c++) {
    __syncthreads();
    int js = c * 64 + sj;
    float* kd = &Ks[sj * 68 + sd];
    float* vd = &Vs[sj * 68 + sd];
    if (js < J_) {
      const u16* kg = Kb + ((size_t)bh * J_ + js) * 64 + sd;
      const u16* vg = Vb + ((size_t)bh * J_ + js) * 64 + sd;
      unp8(*(const uint4*)kg, kd);
      unp8(*(const uint4*)(kg + 8), kd + 8);
      unp8(*(const uint4*)vg, vd);
      unp8(*(const uint4*)(vg + 8), vd + 8);
    } else {
      #pragma unroll
      for (int e = 0; e < 16; e++) { kd[e] = 0.0f; vd[e] = 0.0f; }
    }
    __syncthreads();
    int jb = c * 64;
    for (int jl = g; jl < 64; jl += 4) {
      int jj = jb + jl;
      if (jj <= myq + 2) {                 // causal (null cols 0,1 always visible)
        const float* kr = &Ks[jl * 68];
        float s = 0.0f;
        #pragma unroll
        for (int d = 0; d < 64; d++) s = fmaf(qreg[d], kr[d], s);
        float p = __expf(fmaf(s, 8.0f, slope * (float)(jj - myq - 2)) - Mb);
        l += p;
        const float* vr = &Vs[jl * 68];
        #pragma unroll
        for (int d = 0; d < 64; d++) oreg[d] = fmaf(p, vr[d], oreg[d]);
      }
    }
  }
  __syncthreads();
  lbuf[g * 64 + qi] = l;
  // sequential per-wave merge of O partials into Ks region (aliased after barrier)
  for (int w = 0; w < 4; w++) {
    if (g == w) {
      float* mr = &smem[qi * 68];
      if (w == 0) {
        #pragma unroll
        for (int d = 0; d < 64; d++) mr[d] = oreg[d];
      } else {
        #pragma unroll
        for (int d = 0; d < 64; d++) mr[d] += oreg[d];
      }
    }
    __syncthreads();
  }
  // write (b, n, h, d)
  for (int e = tid; e < 4096; e += 256) {
    int qe = e >> 6, de = e & 63;
    float ls = lbuf[qe] + lbuf[64 + qe] + lbuf[128 + qe] + lbuf[192 + qe];
    float val = smem[qe * 68 + de] / ls;
    AO[(((size_t)(b * N_ + q0 + qe)) * H_ + h) * 64 + de] = f2b(val);
  }
}

// ---------------- launch ----------------
extern "C" void kernel_launch(void* const* d_in, const int* in_sizes, int n_in,
                              void* d_out, int out_size, void* d_ws, size_t ws_size,
                              hipStream_t stream) {
  const float* x    = (const float*)d_in[0];
  const float* ng   = (const float*)d_in[1];
  const float* nb   = (const float*)d_in[2];
  const float* Wq   = (const float*)d_in[3];
  const float* Wkv  = (const float*)d_in[4];
  const float* qs   = (const float*)d_in[5];
  const float* ks   = (const float*)d_in[6];
  const float* nkv  = (const float*)d_in[7];
  const float* Wout = (const float*)d_in[8];
  float* out = (float*)d_out;
  char* ws = (char*)d_ws;

  // workspace layout (bytes); AO reuses the xn region (xn dead after Q-GEMM)
  u16* xbf   = (u16*)(ws + 0);            //  8,388,608  (pre-norm x, bf16)
  u16* xn    = (u16*)(ws + 8388608);      //  8,388,608  (LN(x), bf16)
  u16* WqT   = (u16*)(ws + 16777216);     //  2,097,152
  u16* WkvT  = (u16*)(ws + 18874368);     //  4,194,304
  u16* WoutT = (u16*)(ws + 23068672);     //  2,097,152
  u16* Qraw  = (u16*)(ws + 25165824);     //  8,388,608
  u16* KVraw = (u16*)(ws + 33554432);     // 16,777,216
  u16* Qn    = (u16*)(ws + 50331648);     //  8,388,608
  u16* Kb    = (u16*)(ws + 58720256);     //  8,396,800
  u16* Vb    = (u16*)(ws + 67117056);     //  8,396,800  (end 75,513,856)
  u16* AO    = xn;                        // reuse

  ktranspose_cast<<<dim3(32, 32), 256, 0, stream>>>(Wq, WqT, 1024, 1024);
  ktranspose_cast<<<dim3(64, 32), 256, 0, stream>>>(Wkv, WkvT, 1024, 2048);
  ktranspose_cast<<<dim3(32, 32), 256, 0, stream>>>(Wout, WoutT, 1024, 1024);
  castx_k<<<2048, 256, 0, stream>>>(x, xbf);
  lnorm_k<<<4096, 256, 0, stream>>>(x, ng, nb, xn);
  gemm_bt<false><<<dim3(16, 64), 256, 0, stream>>>(xn, WqT, Qraw, M_, 1024, 1024);
  gemm_bt<false><<<dim3(32, 64), 256, 0, stream>>>(xbf, WkvT, KVraw, M_, 2048, 1024);
  qnorm_k<<<16384, 256, 0, stream>>>(Qraw, qs, Qn);
  kvprep_k<<<16384, 256, 0, stream>>>(KVraw, ks, Kb, Vb);
  nullprep_k<<<1, 256, 0, stream>>>(nkv, ks, Kb, Vb);
  attn_k<<<dim3(32, 32), 256, 0, stream>>>(Qn, Kb, Vb, qs, ks, AO);
  gemm_bt<true><<<dim3(16, 64), 256, 0, stream>>>(AO, WoutT, out, M_, 1024, 1024);
}

// Round 3
// 324.305 us; speedup vs baseline: 4.1299x; 4.1299x over previous
//
#include <hip/hip_runtime.h>
#include <stdint.h>

// Problem constants
#define H_    16
#define N_    2048
#define DIM_  1024
#define DH_   64
#define NN_   2
#define J_    2050     // N + NNULL
#define JP_   2112     // J padded to 33*64 for attention chunk staging
#define B_    2
#define M_    4096     // B * N

typedef unsigned short u16;
typedef short bf16x8 __attribute__((ext_vector_type(8)));
typedef float f32x4 __attribute__((ext_vector_type(4)));

__device__ __forceinline__ float b2f(u16 u) {
  union { unsigned int i; float f; } v; v.i = ((unsigned int)u) << 16; return v.f;
}
__device__ __forceinline__ u16 f2b(float f) {
  union { float f; unsigned int i; } v; v.f = f;
  unsigned int r = v.i + 0x7fffu + ((v.i >> 16) & 1u);   // RNE
  return (u16)(r >> 16);
}
__device__ __forceinline__ float lo2f(unsigned int u) {
  union { unsigned int i; float f; } v; v.i = u << 16; return v.f;
}
__device__ __forceinline__ float hi2f(unsigned int u) {
  union { unsigned int i; float f; } v; v.i = u & 0xffff0000u; return v.f;
}

// ---------------- transpose + cast (fp32 R x C -> bf16 C x R) ----------------
__global__ __launch_bounds__(256) void ktranspose_cast(const float* __restrict__ in,
                                                       u16* __restrict__ out, int R, int C) {
  __shared__ float tile[32][33];
  int tx = threadIdx.x & 31, ty = threadIdx.x >> 5;   // 32 x 8
  int c0 = blockIdx.x * 32, r0 = blockIdx.y * 32;
  #pragma unroll
  for (int i = 0; i < 32; i += 8)
    tile[ty + i][tx] = in[(size_t)(r0 + ty + i) * C + c0 + tx];
  __syncthreads();
  #pragma unroll
  for (int i = 0; i < 32; i += 8)
    out[(size_t)(c0 + ty + i) * R + r0 + tx] = f2b(tile[tx][ty + i]);
}

// ---------------- cast fp32 -> bf16, 8 elems/thread ----------------
__global__ __launch_bounds__(256) void castx_k(const float* __restrict__ in,
                                               u16* __restrict__ out) {
  int i = blockIdx.x * 256 + threadIdx.x;
  float4 a = ((const float4*)in)[2 * i];
  float4 b = ((const float4*)in)[2 * i + 1];
  uint4 o;
  o.x = (unsigned)f2b(a.x) | ((unsigned)f2b(a.y) << 16);
  o.y = (unsigned)f2b(a.z) | ((unsigned)f2b(a.w) << 16);
  o.z = (unsigned)f2b(b.x) | ((unsigned)f2b(b.y) << 16);
  o.w = (unsigned)f2b(b.z) | ((unsigned)f2b(b.w) << 16);
  ((uint4*)out)[i] = o;
}

// ---------------- LayerNorm (fp32 in, bf16 out), row of 1024 ----------------
__global__ __launch_bounds__(256) void lnorm_k(const float* __restrict__ x,
                                               const float* __restrict__ g,
                                               const float* __restrict__ bb,
                                               u16* __restrict__ xn) {
  int row = blockIdx.x;
  int t = threadIdx.x;
  float4 rw = *(const float4*)(x + (size_t)row * DIM_ + t * 4);
  float v0 = rw.x, v1 = rw.y, v2 = rw.z, v3 = rw.w;
  float s = v0 + v1 + v2 + v3;
  float ss = v0 * v0 + v1 * v1 + v2 * v2 + v3 * v3;
  #pragma unroll
  for (int o = 32; o; o >>= 1) { s += __shfl_xor(s, o, 64); ss += __shfl_xor(ss, o, 64); }
  __shared__ float red[8];
  int lane = t & 63, w = t >> 6;
  if (lane == 0) { red[w] = s; red[4 + w] = ss; }
  __syncthreads();
  float S = red[0] + red[1] + red[2] + red[3];
  float SS = red[4] + red[5] + red[6] + red[7];
  float mu = S * (1.0f / DIM_);
  float var = SS * (1.0f / DIM_) - mu * mu;
  float rs = rsqrtf(var + 1e-5f);
  float4 gv = *(const float4*)(g + t * 4);
  float4 bv = *(const float4*)(bb + t * 4);
  uint2 ow;
  ow.x = (unsigned)f2b((v0 - mu) * rs * gv.x + bv.x) |
         ((unsigned)f2b((v1 - mu) * rs * gv.y + bv.y) << 16);
  ow.y = (unsigned)f2b((v2 - mu) * rs * gv.z + bv.z) |
         ((unsigned)f2b((v3 - mu) * rs * gv.w + bv.w) << 16);
  *(uint2*)(xn + (size_t)row * DIM_ + t * 4) = ow;
}

// ---------------- MFMA GEMM: C[MxNc] = A[MxK] * BT[NcxK]^T ----------------
template <bool F32OUT>
__global__ __launch_bounds__(256) void gemm_bt(const u16* __restrict__ A,
                                               const u16* __restrict__ BT,
                                               void* __restrict__ Cv,
                                               int M, int Nc, int K) {
  __shared__ u16 As[64][40];
  __shared__ u16 Bs[64][40];
  int tid = threadIdx.x;
  int wv = tid >> 6, lane = tid & 63;
  int row0 = blockIdx.y * 64, col0 = blockIdx.x * 64;
  f32x4 acc[4] = {};
  int sr = tid >> 2;
  int sk = (tid & 3) * 8;
  const u16* Ag = A + (size_t)(row0 + sr) * K + sk;
  const u16* Bg = BT + (size_t)(col0 + sr) * K + sk;
  int fm = lane & 15;
  int fk = (lane >> 4) * 8;
  for (int k0 = 0; k0 < K; k0 += 32) {
    *(uint4*)(&As[sr][sk]) = *(const uint4*)(Ag + k0);
    *(uint4*)(&Bs[sr][sk]) = *(const uint4*)(Bg + k0);
    __syncthreads();
    bf16x8 af = *(const bf16x8*)(&As[wv * 16 + fm][fk]);
    #pragma unroll
    for (int nt = 0; nt < 4; nt++) {
      bf16x8 bfr = *(const bf16x8*)(&Bs[nt * 16 + fm][fk]);
      acc[nt] = __builtin_amdgcn_mfma_f32_16x16x32_bf16(af, bfr, acc[nt], 0, 0, 0);
    }
    __syncthreads();
  }
  int cn = lane & 15, cr = (lane >> 4) * 4;
  #pragma unroll
  for (int nt = 0; nt < 4; nt++) {
    #pragma unroll
    for (int r = 0; r < 4; r++) {
      int m = row0 + wv * 16 + cr + r;
      int n = col0 + nt * 16 + cn;
      if (F32OUT) ((float*)Cv)[(size_t)m * Nc + n] = acc[nt][r];
      else        ((u16*)Cv)[(size_t)m * Nc + n] = f2b(acc[nt][r]);
    }
  }
}

// ---------------- Q l2norm + scale, relayout to (b,h,n,d) ----------------
__global__ __launch_bounds__(256) void qnorm_k(const u16* __restrict__ Qraw,
                                               const float* __restrict__ qs,
                                               u16* __restrict__ Qn) {
  int wid = blockIdx.x * 4 + (threadIdx.x >> 6);
  int lane = threadIdx.x & 63;
  int r = wid >> 4, h = wid & 15;
  float v = b2f(Qraw[(size_t)r * 1024 + h * 64 + lane]);
  float ss = v * v;
  #pragma unroll
  for (int o = 32; o; o >>= 1) ss += __shfl_xor(ss, o, 64);
  float dn = fmaxf(sqrtf(ss), 1e-12f);
  float res = v / dn * qs[lane];
  int b = r >> 11, n = r & 2047;
  Qn[(((size_t)(b * H_ + h)) * N_ + n) * 64 + lane] = f2b(res);
}

// ---------------- K l2norm+scale & V copy, relayout to (b,h,j,d), j offset NN ----------------
__global__ __launch_bounds__(256) void kvprep_k(const u16* __restrict__ KVraw,
                                                const float* __restrict__ ks,
                                                u16* __restrict__ Kb, u16* __restrict__ Vb) {
  int wid = blockIdx.x * 4 + (threadIdx.x >> 6);
  int lane = threadIdx.x & 63;
  int r = wid >> 4, h = wid & 15;
  float kv = b2f(KVraw[(size_t)r * 2048 + h * 64 + lane]);
  float ss = kv * kv;
  #pragma unroll
  for (int o = 32; o; o >>= 1) ss += __shfl_xor(ss, o, 64);
  float dn = fmaxf(sqrtf(ss), 1e-12f);
  float res = kv / dn * ks[lane];
  int b = r >> 11, n = r & 2047;
  size_t o = (((size_t)(b * H_ + h)) * J_ + (n + NN_)) * 64 + lane;
  Kb[o] = f2b(res);
  Vb[o] = KVraw[(size_t)r * 2048 + 1024 + h * 64 + lane];
}

// ---------------- null KV ----------------
__global__ __launch_bounds__(256) void nullprep_k(const float* __restrict__ nkv,
                                                  const float* __restrict__ ks,
                                                  u16* __restrict__ Kb, u16* __restrict__ Vb) {
  int w = threadIdx.x >> 6, lane = threadIdx.x & 63;
  for (int t = w; t < B_ * H_ * NN_; t += 4) {
    int b = t >> 5, h = (t >> 1) & 15, i = t & 1;
    float kv = nkv[(size_t)(h * 4 + 2 * i) * 64 + lane];
    float ss = kv * kv;
    #pragma unroll
    for (int o = 32; o; o >>= 1) ss += __shfl_xor(ss, o, 64);
    float dn = fmaxf(sqrtf(ss), 1e-12f);
    size_t o = (((size_t)(b * H_ + h)) * J_ + i) * 64 + lane;
    Kb[o] = f2b(kv / dn * ks[lane]);
    Vb[o] = f2b(nkv[(size_t)(h * 4 + 2 * i + 1) * 64 + lane]);
  }
}

// ---------------- V transpose: (b,h,j,d) -> (b,h,d,jPadded), zero-fill j>=J ----------------
__global__ __launch_bounds__(256) void vtrans_k(const u16* __restrict__ Vb,
                                                u16* __restrict__ VT) {
  __shared__ u16 tile[64][72];
  int t = threadIdx.x;
  int jt = blockIdx.x;          // 0..32
  int bh = blockIdx.y;
  int j = t >> 2, dg = (t & 3) * 16;
  int jg = jt * 64 + j;
  uint4 z = {0, 0, 0, 0};
  uint4 a = z, b4 = z;
  if (jg < J_) {
    const uint4* src = (const uint4*)(Vb + ((size_t)bh * J_ + jg) * 64 + dg);
    a = src[0]; b4 = src[1];
  }
  *(uint4*)&tile[j][dg] = a;
  *(uint4*)&tile[j][dg + 8] = b4;
  __syncthreads();
  int d = t >> 2, jg4 = (t & 3) * 16;
  u16 tmp[16] __attribute__((aligned(16)));
  #pragma unroll
  for (int i = 0; i < 16; i++) tmp[i] = tile[jg4 + i][d];
  uint4* dst = (uint4*)(VT + ((size_t)bh * 64 + d) * JP_ + jt * 64 + jg4);
  dst[0] = ((uint4*)tmp)[0];
  dst[1] = ((uint4*)tmp)[1];
}

// ---------------- MFMA flash attention ----------------
// block: 4 waves x 16 q-rows = 64 q-rows per block. grid (32 qtiles, 32 bh).
// Fixed-cap softmax: Mb = 8*max_d|qs_d*ks_d| bounds all scores (unit q,k + bias<=0)
// -> no online rescale; l and O partials are plain sums across chunks.
__global__ __launch_bounds__(256, 4) void attn_k(const u16* __restrict__ Qn,
                                                 const u16* __restrict__ Kb,
                                                 const u16* __restrict__ VT,
                                                 const float* __restrict__ qs,
                                                 const float* __restrict__ ks,
                                                 u16* __restrict__ AO) {
  __shared__ u16 Ks[64][72];          // K chunk, rows j, cols d
  __shared__ u16 Vs[64][72];          // V^T chunk, rows d, cols j
  __shared__ u16 Ps[4][16][72];       // per-wave P (16 q-rows x 64 j)
  int tid = threadIdx.x;
  int wv = tid >> 6, lane = tid & 63;
  int bh = blockIdx.y, h = bh & 15, b = bh >> 4;
  int qt = 31 - blockIdx.x;           // longest blocks launch first
  int q0 = qt * 64;
  float slope = exp2f(-0.5f * (float)(h + 1));
  float prod = fabsf(qs[lane] * ks[lane]);
  #pragma unroll
  for (int o = 32; o; o >>= 1) prod = fmaxf(prod, __shfl_xor(prod, o, 64));
  float Mb = 8.0f * prod;
  int fm = lane & 15, fg = lane >> 4;
  // Q fragments (A-operand: m=fm, k=fg*8.. ; two K-steps)
  const u16* qp = Qn + (((size_t)bh * N_) + q0 + wv * 16 + fm) * 64 + fg * 8;
  bf16x8 qf0 = *(const bf16x8*)(qp);
  bf16x8 qf1 = *(const bf16x8*)(qp + 32);
  f32x4 accO[4] = {};
  float lp[4] = {0.f, 0.f, 0.f, 0.f};
  int sj = tid >> 2, sd4 = (tid & 3) * 16;
  int nch = qt + 2;
  const u16* KbBH = Kb + (size_t)bh * J_ * 64;
  const u16* VTbh = VT + (size_t)bh * 64 * JP_;
  for (int c = 0; c < nch; c++) {
    int jb = c * 64;
    __syncthreads();
    int js = jb + sj;
    if (js < J_) {
      const uint4* kg = (const uint4*)(KbBH + (size_t)js * 64 + sd4);
      *(uint4*)&Ks[sj][sd4] = kg[0];
      *(uint4*)&Ks[sj][sd4 + 8] = kg[1];
    } else {
      uint4 z = {0, 0, 0, 0};
      *(uint4*)&Ks[sj][sd4] = z;
      *(uint4*)&Ks[sj][sd4 + 8] = z;
    }
    {
      const uint4* vg = (const uint4*)(VTbh + (size_t)sj * JP_ + jb + sd4);
      *(uint4*)&Vs[sj][sd4] = vg[0];
      *(uint4*)&Vs[sj][sd4 + 8] = vg[1];
    }
    __syncthreads();
    // S = Q K^T   (A=Q m=q, B=K n=j)
    f32x4 accS[4] = {};
    #pragma unroll
    for (int nt = 0; nt < 4; nt++) {
      bf16x8 kf0 = *(const bf16x8*)&Ks[nt * 16 + fm][fg * 8];
      accS[nt] = __builtin_amdgcn_mfma_f32_16x16x32_bf16(qf0, kf0, accS[nt], 0, 0, 0);
      bf16x8 kf1 = *(const bf16x8*)&Ks[nt * 16 + fm][32 + fg * 8];
      accS[nt] = __builtin_amdgcn_mfma_f32_16x16x32_bf16(qf1, kf1, accS[nt], 0, 0, 0);
    }
    // softmax (fixed cap), write P to per-wave LDS in A-layout source form
    #pragma unroll
    for (int nt = 0; nt < 4; nt++) {
      #pragma unroll
      for (int r = 0; r < 4; r++) {
        int rowl = fg * 4 + r;                 // row within wave tile
        int row = q0 + wv * 16 + rowl;
        int jj = jb + nt * 16 + fm;
        float arg = fmaf(accS[nt][r], 8.0f, slope * (float)(jj - row - 2)) - Mb;
        float p = __expf(arg);
        p = (jj <= row + 2) ? p : 0.0f;
        u16 pb = f2b(p);
        Ps[wv][rowl][nt * 16 + fm] = pb;
        lp[r] += b2f(pb);
      }
    }
    // PV: A=P (m=q,k=j), B=V^T (n=d,k=j)
    bf16x8 pf0 = *(const bf16x8*)&Ps[wv][fm][fg * 8];
    bf16x8 pf1 = *(const bf16x8*)&Ps[wv][fm][32 + fg * 8];
    #pragma unroll
    for (int nt = 0; nt < 4; nt++) {
      bf16x8 vf0 = *(const bf16x8*)&Vs[nt * 16 + fm][fg * 8];
      accO[nt] = __builtin_amdgcn_mfma_f32_16x16x32_bf16(pf0, vf0, accO[nt], 0, 0, 0);
      bf16x8 vf1 = *(const bf16x8*)&Vs[nt * 16 + fm][32 + fg * 8];
      accO[nt] = __builtin_amdgcn_mfma_f32_16x16x32_bf16(pf1, vf1, accO[nt], 0, 0, 0);
    }
  }
  // reduce l across the 16 lanes holding each row's columns
  #pragma unroll
  for (int o = 1; o <= 8; o <<= 1) {
    #pragma unroll
    for (int r = 0; r < 4; r++) lp[r] += __shfl_xor(lp[r], o, 64);
  }
  // write (b, n, h, d)
  #pragma unroll
  for (int nt = 0; nt < 4; nt++) {
    #pragma unroll
    for (int r = 0; r < 4; r++) {
      int row = q0 + wv * 16 + fg * 4 + r;
      float val = accO[nt][r] / lp[r];
      AO[(((size_t)(b * N_ + row)) * H_ + h) * 64 + nt * 16 + fm] = f2b(val);
    }
  }
}

// ---------------- launch ----------------
extern "C" void kernel_launch(void* const* d_in, const int* in_sizes, int n_in,
                              void* d_out, int out_size, void* d_ws, size_t ws_size,
                              hipStream_t stream) {
  const float* x    = (const float*)d_in[0];
  const float* ng   = (const float*)d_in[1];
  const float* nb   = (const float*)d_in[2];
  const float* Wq   = (const float*)d_in[3];
  const float* Wkv  = (const float*)d_in[4];
  const float* qs   = (const float*)d_in[5];
  const float* ks   = (const float*)d_in[6];
  const float* nkv  = (const float*)d_in[7];
  const float* Wout = (const float*)d_in[8];
  float* out = (float*)d_out;
  char* ws = (char*)d_ws;

  u16* xbf   = (u16*)(ws + 0);            //  8,388,608
  u16* xn    = (u16*)(ws + 8388608);      //  8,388,608
  u16* WqT   = (u16*)(ws + 16777216);     //  2,097,152
  u16* WkvT  = (u16*)(ws + 18874368);     //  4,194,304
  u16* WoutT = (u16*)(ws + 23068672);     //  2,097,152
  u16* Qraw  = (u16*)(ws + 25165824);     //  8,388,608
  u16* KVraw = (u16*)(ws + 33554432);     // 16,777,216 (dead after kvprep)
  u16* Qn    = (u16*)(ws + 50331648);     //  8,388,608
  u16* Kb    = (u16*)(ws + 58720256);     //  8,396,800
  u16* Vb    = (u16*)(ws + 67117056);     //  8,396,800  (end 75,513,856)
  u16* VT    = KVraw;                     //  8,650,752 (reuses KVraw region)
  u16* AO    = xn;                        // reuse (xn dead after Q-GEMM)

  ktranspose_cast<<<dim3(32, 32), 256, 0, stream>>>(Wq, WqT, 1024, 1024);
  ktranspose_cast<<<dim3(64, 32), 256, 0, stream>>>(Wkv, WkvT, 1024, 2048);
  ktranspose_cast<<<dim3(32, 32), 256, 0, stream>>>(Wout, WoutT, 1024, 1024);
  castx_k<<<2048, 256, 0, stream>>>(x, xbf);
  lnorm_k<<<4096, 256, 0, stream>>>(x, ng, nb, xn);
  gemm_bt<false><<<dim3(16, 64), 256, 0, stream>>>(xn, WqT, Qraw, M_, 1024, 1024);
  gemm_bt<false><<<dim3(32, 64), 256, 0, stream>>>(xbf, WkvT, KVraw, M_, 2048, 1024);
  qnorm_k<<<16384, 256, 0, stream>>>(Qraw, qs, Qn);
  kvprep_k<<<16384, 256, 0, stream>>>(KVraw, ks, Kb, Vb);
  nullprep_k<<<1, 256, 0, stream>>>(nkv, ks, Kb, Vb);
  vtrans_k<<<dim3(33, 32), 256, 0, stream>>>(Vb, VT);
  attn_k<<<dim3(32, 32), 256, 0, stream>>>(Qn, Kb, VT, qs, ks, AO);
  gemm_bt<true><<<dim3(16, 64), 256, 0, stream>>>(AO, WoutT, out, M_, 1024, 1024);
}

// Round 4
// 292.761 us; speedup vs baseline: 4.5749x; 1.1077x over previous
//
#include <hip/hip_runtime.h>
#include <stdint.h>

// Problem constants
#define H_    16
#define N_    2048
#define DIM_  1024
#define DH_   64
#define NN_   2
#define J_    2050     // N + NNULL
#define JP_   2112     // 33*64, padded j for permuted V^T
#define B_    2
#define M_    4096     // B * N

typedef unsigned short u16;
typedef short bf16x8 __attribute__((ext_vector_type(8)));
typedef float f32x4 __attribute__((ext_vector_type(4)));

__device__ __forceinline__ u16 f2b(float f) {
  union { float f; unsigned int i; } v; v.f = f;
  unsigned int r = v.i + 0x7fffu + ((v.i >> 16) & 1u);   // RNE
  return (u16)(r >> 16);
}
__device__ __forceinline__ float b2f(u16 u) {
  union { unsigned int i; float f; } v; v.i = ((unsigned int)u) << 16; return v.f;
}

// ---------------- transpose + cast (fp32 R x C -> bf16 C x R) ----------------
__global__ __launch_bounds__(256) void ktranspose_cast(const float* __restrict__ in,
                                                       u16* __restrict__ out, int R, int C) {
  __shared__ float tile[32][33];
  int tx = threadIdx.x & 31, ty = threadIdx.x >> 5;   // 32 x 8
  int c0 = blockIdx.x * 32, r0 = blockIdx.y * 32;
  #pragma unroll
  for (int i = 0; i < 32; i += 8)
    tile[ty + i][tx] = in[(size_t)(r0 + ty + i) * C + c0 + tx];
  __syncthreads();
  #pragma unroll
  for (int i = 0; i < 32; i += 8)
    out[(size_t)(c0 + ty + i) * R + r0 + tx] = f2b(tile[tx][ty + i]);
}

// ---------- LayerNorm (fp32 in) -> xn (bf16 LN) + xbf (bf16 cast of x) ----------
__global__ __launch_bounds__(256) void lnorm_k(const float* __restrict__ x,
                                               const float* __restrict__ g,
                                               const float* __restrict__ bb,
                                               u16* __restrict__ xn,
                                               u16* __restrict__ xbf) {
  int row = blockIdx.x;
  int t = threadIdx.x;
  float4 rw = *(const float4*)(x + (size_t)row * DIM_ + t * 4);
  float v0 = rw.x, v1 = rw.y, v2 = rw.z, v3 = rw.w;
  // raw cast out
  uint2 cw;
  cw.x = (unsigned)f2b(v0) | ((unsigned)f2b(v1) << 16);
  cw.y = (unsigned)f2b(v2) | ((unsigned)f2b(v3) << 16);
  *(uint2*)(xbf + (size_t)row * DIM_ + t * 4) = cw;
  float s = v0 + v1 + v2 + v3;
  float ss = v0 * v0 + v1 * v1 + v2 * v2 + v3 * v3;
  #pragma unroll
  for (int o = 32; o; o >>= 1) { s += __shfl_xor(s, o, 64); ss += __shfl_xor(ss, o, 64); }
  __shared__ float red[8];
  int lane = t & 63, w = t >> 6;
  if (lane == 0) { red[w] = s; red[4 + w] = ss; }
  __syncthreads();
  float S = red[0] + red[1] + red[2] + red[3];
  float SS = red[4] + red[5] + red[6] + red[7];
  float mu = S * (1.0f / DIM_);
  float var = SS * (1.0f / DIM_) - mu * mu;
  float rs = rsqrtf(var + 1e-5f);
  float4 gv = *(const float4*)(g + t * 4);
  float4 bv = *(const float4*)(bb + t * 4);
  uint2 ow;
  ow.x = (unsigned)f2b((v0 - mu) * rs * gv.x + bv.x) |
         ((unsigned)f2b((v1 - mu) * rs * gv.y + bv.y) << 16);
  ow.y = (unsigned)f2b((v2 - mu) * rs * gv.z + bv.z) |
         ((unsigned)f2b((v3 - mu) * rs * gv.w + bv.w) << 16);
  *(uint2*)(xn + (size_t)row * DIM_ + t * 4) = ow;
}

// ---------------- MFMA GEMM, tile 128m x 64n, K-step 32 ----------------
// MODE 1: fp32 row-major -> dst0
// MODE 2: per-row l2norm over the 64-col head, * scale[d], write Qn (b,h,n,d)
// MODE 3: cols<1024 = K half: l2norm * ks -> Kb (b,h,j=n+2,d); cols>=1024 = V half:
//         plain bf16 -> Vb (b,h,j=n+2,d)
template <int MODE>
__global__ __launch_bounds__(256) void gemm_k(const u16* __restrict__ A,
                                              const u16* __restrict__ BT,
                                              void* __restrict__ dst0,
                                              void* __restrict__ dst1,
                                              const float* __restrict__ scale,
                                              int M, int Nc, int K) {
  __shared__ u16 As[128][40];
  __shared__ u16 Bs[64][40];
  int tid = threadIdx.x, wv = tid >> 6, lane = tid & 63;
  int fm = lane & 15, fg = lane >> 4;
  int row0 = blockIdx.y * 128, col0 = blockIdx.x * 64;
  f32x4 acc[2][4] = {};
  int sr = tid >> 1, sk = (tid & 1) * 16;
  const u16* Ag = A + (size_t)(row0 + sr) * K + sk;
  const u16* Bg = BT + (size_t)(col0 + (sr & 63)) * K + sk;
  bool doB = tid < 128;
  for (int k0 = 0; k0 < K; k0 += 32) {
    __syncthreads();
    *(uint4*)&As[sr][sk] = *(const uint4*)(Ag + k0);
    *(uint4*)&As[sr][sk + 8] = *(const uint4*)(Ag + k0 + 8);
    if (doB) {
      *(uint4*)&Bs[sr][sk] = *(const uint4*)(Bg + k0);
      *(uint4*)&Bs[sr][sk + 8] = *(const uint4*)(Bg + k0 + 8);
    }
    __syncthreads();
    bf16x8 af0 = *(const bf16x8*)&As[wv * 32 + fm][fg * 8];
    bf16x8 af1 = *(const bf16x8*)&As[wv * 32 + 16 + fm][fg * 8];
    #pragma unroll
    for (int nt = 0; nt < 4; nt++) {
      bf16x8 bfr = *(const bf16x8*)&Bs[nt * 16 + fm][fg * 8];
      acc[0][nt] = __builtin_amdgcn_mfma_f32_16x16x32_bf16(af0, bfr, acc[0][nt], 0, 0, 0);
      acc[1][nt] = __builtin_amdgcn_mfma_f32_16x16x32_bf16(af1, bfr, acc[1][nt], 0, 0, 0);
    }
  }
  // C/D layout: col = fm (n), row = fg*4 + r (m within 16-tile)
  if (MODE == 1) {
    float* C = (float*)dst0;
    #pragma unroll
    for (int mt = 0; mt < 2; mt++)
      #pragma unroll
      for (int nt = 0; nt < 4; nt++)
        #pragma unroll
        for (int r = 0; r < 4; r++) {
          int m = row0 + wv * 32 + mt * 16 + fg * 4 + r;
          C[(size_t)m * Nc + col0 + nt * 16 + fm] = acc[mt][nt][r];
        }
  } else {
    bool isK = (MODE == 2) || (col0 < 1024);
    int h = ((MODE == 2) ? col0 : (isK ? col0 : col0 - 1024)) >> 6;
    float sv[4];
    if (isK) {
      #pragma unroll
      for (int nt = 0; nt < 4; nt++) sv[nt] = scale[nt * 16 + fm];
    }
    u16* Do = (u16*)((MODE == 3 && !isK) ? dst1 : dst0);
    #pragma unroll
    for (int mt = 0; mt < 2; mt++) {
      #pragma unroll
      for (int r = 0; r < 4; r++) {
        float inv = 1.0f;
        if (isK) {
          float ssp = 0.0f;
          #pragma unroll
          for (int nt = 0; nt < 4; nt++) ssp += acc[mt][nt][r] * acc[mt][nt][r];
          #pragma unroll
          for (int o = 1; o <= 8; o <<= 1) ssp += __shfl_xor(ssp, o, 64);
          inv = 1.0f / fmaxf(sqrtf(ssp), 1e-12f);
        }
        int m = row0 + wv * 32 + mt * 16 + fg * 4 + r;
        int b = m >> 11, n = m & 2047;
        size_t base;
        if (MODE == 2) base = (((size_t)(b * H_ + h)) * N_ + n) * 64;
        else           base = (((size_t)(b * H_ + h)) * J_ + (n + NN_)) * 64;
        #pragma unroll
        for (int nt = 0; nt < 4; nt++) {
          float val = acc[mt][nt][r];
          if (isK) val = val * inv * sv[nt];
          Do[base + nt * 16 + fm] = f2b(val);
        }
      }
    }
  }
}

// ------- V transpose+permute: Vb (b,h,j,d) + null kv -> VTp (b,h,d,pos) ; also Kb j<2 -------
// VTp[bh][d][c*64+pos] = V[bh][c*64 + pi(pos)][d],
// pi(pos): h2=pos>>5, fgp=(pos>>3)&3, nt=(pos>>2)&1, r=pos&3 -> j = (h2*2+nt)*16 + fgp*4 + r
__global__ __launch_bounds__(256) void vtransp_k(const u16* __restrict__ Vb,
                                                 const float* __restrict__ nkv,
                                                 const float* __restrict__ ks,
                                                 u16* __restrict__ Kb,
                                                 u16* __restrict__ VTp) {
  __shared__ u16 tile[64][80];
  int t = threadIdx.x;
  int c = blockIdx.x, bh = blockIdx.y, h = bh & 15;
  int jl = t >> 2, dc = (t & 3) * 16;
  int j = c * 64 + jl;
  if (j < NN_) {
    float kvv[16];
    float kssp = 0.0f;
    #pragma unroll
    for (int e = 0; e < 16; e++) {
      float vv = nkv[(size_t)(h * 4 + 2 * j + 1) * 64 + dc + e];
      tile[jl][dc + e] = f2b(vv);
      float kv = nkv[(size_t)(h * 4 + 2 * j) * 64 + dc + e];
      kvv[e] = kv; kssp += kv * kv;
    }
    kssp += __shfl_xor(kssp, 1, 64);
    kssp += __shfl_xor(kssp, 2, 64);
    float inv = 1.0f / fmaxf(sqrtf(kssp), 1e-12f);
    #pragma unroll
    for (int e = 0; e < 16; e++)
      Kb[((size_t)bh * J_ + j) * 64 + dc + e] = f2b(kvv[e] * inv * ks[dc + e]);
  } else if (j < J_) {
    const uint4* src = (const uint4*)(Vb + ((size_t)bh * J_ + j) * 64 + dc);
    *(uint4*)&tile[jl][dc] = src[0];
    *(uint4*)&tile[jl][dc + 8] = src[1];
  } else {
    uint4 z = {0, 0, 0, 0};
    *(uint4*)&tile[jl][dc] = z;
    *(uint4*)&tile[jl][dc + 8] = z;
  }
  __syncthreads();
  int d = t >> 2, p0 = (t & 3) * 16;
  u16 tmp[16] __attribute__((aligned(16)));
  #pragma unroll
  for (int e = 0; e < 16; e++) {
    int pos = p0 + e;
    int h2 = pos >> 5, rem = pos & 31;
    int fgp = rem >> 3, tt = rem & 7;
    int nt = tt >> 2, r = tt & 3;
    int jloc = (h2 * 2 + nt) * 16 + fgp * 4 + r;
    tmp[e] = tile[jloc][d];
  }
  uint4* dstp = (uint4*)(VTp + ((size_t)bh * 64 + d) * JP_ + c * 64 + p0);
  dstp[0] = ((uint4*)tmp)[0];
  dstp[1] = ((uint4*)tmp)[1];
}

// ---------------- MFMA flash attention, S^T form, P stays in registers ----------------
// S^T = K*Q^T (A=K m=j, B=Q n=q). C-layout: lane holds q=fm, j = nt*16+fg*4+r.
// PV: O^T = V^T * P^T with k-space permuted by pi (baked into VTp): B-frag for P^T is
// exactly the softmaxed accS in-lane. Fixed-cap softmax (Mb bound via Cauchy-Schwarz).
__global__ __launch_bounds__(256, 4) void attn_k(const u16* __restrict__ Qn,
                                                 const u16* __restrict__ Kb,
                                                 const u16* __restrict__ VTp,
                                                 const float* __restrict__ qs,
                                                 const float* __restrict__ ks,
                                                 u16* __restrict__ AO) {
  __shared__ u16 Ks[64][80];
  __shared__ u16 Vsp[64][80];
  int tid = threadIdx.x;
  int wv = tid >> 6, lane = tid & 63;
  int fm = lane & 15, fg = lane >> 4;
  int bh = blockIdx.y, h = bh & 15, b = bh >> 4;
  int qt = 31 - blockIdx.x;           // longest blocks first
  int q0 = qt * 64;
  int q = q0 + wv * 16 + fm;
  float slope = exp2f(-0.5f * (float)(h + 1));
  float prod = fabsf(qs[lane] * ks[lane]);
  #pragma unroll
  for (int o = 32; o; o >>= 1) prod = fmaxf(prod, __shfl_xor(prod, o, 64));
  float Mb = 8.0f * prod;
  const u16* qp = Qn + ((size_t)bh * N_ + q) * 64 + fg * 8;
  bf16x8 qf0 = *(const bf16x8*)(qp);
  bf16x8 qf1 = *(const bf16x8*)(qp + 32);
  f32x4 accO[4] = {};
  float lp = 0.0f;
  int sj = tid >> 2, sd4 = (tid & 3) * 16;
  int nch = qt + 2;
  const u16* KbBH = Kb + (size_t)bh * J_ * 64;
  const u16* VTbh = VTp + (size_t)bh * 64 * JP_;
  for (int c = 0; c < nch; c++) {
    int jb = c * 64;
    __syncthreads();
    int js = jb + sj;
    if (js < J_) {
      const uint4* kg = (const uint4*)(KbBH + (size_t)js * 64 + sd4);
      *(uint4*)&Ks[sj][sd4] = kg[0];
      *(uint4*)&Ks[sj][sd4 + 8] = kg[1];
    } else {
      uint4 z = {0, 0, 0, 0};
      *(uint4*)&Ks[sj][sd4] = z;
      *(uint4*)&Ks[sj][sd4 + 8] = z;
    }
    {
      const uint4* vg = (const uint4*)(VTbh + (size_t)sj * JP_ + jb + sd4);
      *(uint4*)&Vsp[sj][sd4] = vg[0];
      *(uint4*)&Vsp[sj][sd4 + 8] = vg[1];
    }
    __syncthreads();
    // S^T = K Q^T
    f32x4 accS[4] = {};
    #pragma unroll
    for (int nt = 0; nt < 4; nt++) {
      bf16x8 kf0 = *(const bf16x8*)&Ks[nt * 16 + fm][fg * 8];
      accS[nt] = __builtin_amdgcn_mfma_f32_16x16x32_bf16(kf0, qf0, accS[nt], 0, 0, 0);
      bf16x8 kf1 = *(const bf16x8*)&Ks[nt * 16 + fm][32 + fg * 8];
      accS[nt] = __builtin_amdgcn_mfma_f32_16x16x32_bf16(kf1, qf1, accS[nt], 0, 0, 0);
    }
    // softmax in-register; pack P^T B-frags
    union { bf16x8 v; u16 s[8]; } P0, P1;
    #pragma unroll
    for (int nt = 0; nt < 4; nt++) {
      #pragma unroll
      for (int r = 0; r < 4; r++) {
        int jj = jb + nt * 16 + fg * 4 + r;
        float arg = fmaf(accS[nt][r], 8.0f, slope * (float)(jj - q - 2)) - Mb;
        float p = (jj <= q + 2) ? __expf(arg) : 0.0f;
        u16 pb = f2b(p);
        lp += b2f(pb);
        if (nt < 2) P0.s[nt * 4 + r] = pb;
        else        P1.s[(nt - 2) * 4 + r] = pb;
      }
    }
    // O^T += V^T P^T (permuted k-space)
    #pragma unroll
    for (int nt = 0; nt < 4; nt++) {
      bf16x8 vf0 = *(const bf16x8*)&Vsp[nt * 16 + fm][fg * 8];
      accO[nt] = __builtin_amdgcn_mfma_f32_16x16x32_bf16(vf0, P0.v, accO[nt], 0, 0, 0);
      bf16x8 vf1 = *(const bf16x8*)&Vsp[nt * 16 + fm][32 + fg * 8];
      accO[nt] = __builtin_amdgcn_mfma_f32_16x16x32_bf16(vf1, P1.v, accO[nt], 0, 0, 0);
    }
  }
  lp += __shfl_xor(lp, 16, 64);
  lp += __shfl_xor(lp, 32, 64);
  float linv = 1.0f / lp;
  // accO C-layout: col q=fm, row d = nt*16 + fg*4 + r  -> pack 4 consecutive d
  size_t rowbase = ((size_t)(b * N_ + q)) * (H_ * 64) + h * 64;
  #pragma unroll
  for (int nt = 0; nt < 4; nt++) {
    uint2 ow;
    ow.x = (unsigned)f2b(accO[nt][0] * linv) | ((unsigned)f2b(accO[nt][1] * linv) << 16);
    ow.y = (unsigned)f2b(accO[nt][2] * linv) | ((unsigned)f2b(accO[nt][3] * linv) << 16);
    *(uint2*)(AO + rowbase + nt * 16 + fg * 4) = ow;
  }
}

// ---------------- launch ----------------
extern "C" void kernel_launch(void* const* d_in, const int* in_sizes, int n_in,
                              void* d_out, int out_size, void* d_ws, size_t ws_size,
                              hipStream_t stream) {
  const float* x    = (const float*)d_in[0];
  const float* ng   = (const float*)d_in[1];
  const float* nb   = (const float*)d_in[2];
  const float* Wq   = (const float*)d_in[3];
  const float* Wkv  = (const float*)d_in[4];
  const float* qs   = (const float*)d_in[5];
  const float* ks   = (const float*)d_in[6];
  const float* nkv  = (const float*)d_in[7];
  const float* Wout = (const float*)d_in[8];
  float* out = (float*)d_out;
  char* ws = (char*)d_ws;

  u16* xbf   = (u16*)(ws + 0);            //  8,388,608
  u16* xn    = (u16*)(ws + 8388608);      //  8,388,608 (AO reuses after Q-GEMM)
  u16* WqT   = (u16*)(ws + 16777216);     //  2,097,152
  u16* WkvT  = (u16*)(ws + 18874368);     //  4,194,304
  u16* WoutT = (u16*)(ws + 23068672);     //  2,097,152
  u16* Qn    = (u16*)(ws + 25165824);     //  8,388,608
  u16* Vb    = (u16*)(ws + 33554432);     //  8,396,800
  u16* Kb    = (u16*)(ws + 41951232);     //  8,396,800
  u16* VTp   = (u16*)(ws + 50348032);     //  8,650,752 (end 58,998,784)
  u16* AO    = xn;

  ktranspose_cast<<<dim3(32, 32), 256, 0, stream>>>(Wq, WqT, 1024, 1024);
  ktranspose_cast<<<dim3(64, 32), 256, 0, stream>>>(Wkv, WkvT, 1024, 2048);
  ktranspose_cast<<<dim3(32, 32), 256, 0, stream>>>(Wout, WoutT, 1024, 1024);
  lnorm_k<<<4096, 256, 0, stream>>>(x, ng, nb, xn, xbf);
  gemm_k<2><<<dim3(16, 32), 256, 0, stream>>>(xn, WqT, Qn, nullptr, qs, M_, 1024, 1024);
  gemm_k<3><<<dim3(32, 32), 256, 0, stream>>>(xbf, WkvT, Kb, Vb, ks, M_, 2048, 1024);
  vtransp_k<<<dim3(33, 32), 256, 0, stream>>>(Vb, nkv, ks, Kb, VTp);
  attn_k<<<dim3(32, 32), 256, 0, stream>>>(Qn, Kb, VTp, qs, ks, AO);
  gemm_k<1><<<dim3(16, 32), 256, 0, stream>>>(AO, WoutT, out, nullptr, nullptr, M_, 1024, 1024);
}

// Round 5
// 238.807 us; speedup vs baseline: 5.6085x; 1.2259x over previous
//
#include <hip/hip_runtime.h>
#include <stdint.h>

// Problem constants
#define H_    16
#define N_    2048
#define DIM_  1024
#define DH_   64
#define NN_   2
#define J_    2050     // N + NNULL
#define JP_   2112     // 33*64, padded j (Kb zero tail via memset, VTp zero-filled)
#define B_    2
#define M_    4096     // B * N
#define NSEG_ 84       // sum over qt of ceil((qt+2)/8)

typedef unsigned short u16;
typedef unsigned int u32;
typedef short bf16x8 __attribute__((ext_vector_type(8)));
typedef float f32x4 __attribute__((ext_vector_type(4)));

__device__ __forceinline__ u16 f2b(float f) {
  union { float f; unsigned int i; } v; v.f = f;
  unsigned int r = v.i + 0x7fffu + ((v.i >> 16) & 1u);   // RNE
  return (u16)(r >> 16);
}
__device__ __forceinline__ float b2f(u16 u) {
  union { unsigned int i; float f; } v; v.i = ((unsigned int)u) << 16; return v.f;
}
__device__ __forceinline__ float lo2f(u32 u) {
  union { u32 i; float f; } v; v.i = u << 16; return v.f;
}
__device__ __forceinline__ float hi2f(u32 u) {
  union { u32 i; float f; } v; v.i = u & 0xffff0000u; return v.f;
}
__device__ __forceinline__ void unp8(const uint4 u, float* d) {
  d[0] = lo2f(u.x); d[1] = hi2f(u.x); d[2] = lo2f(u.y); d[3] = hi2f(u.y);
  d[4] = lo2f(u.z); d[5] = hi2f(u.z); d[6] = lo2f(u.w); d[7] = hi2f(u.w);
}
// async global->LDS DMA, 16B/lane; LDS dest = wave-uniform base + lane*16
__device__ __forceinline__ void dma16(const u16* g, u16* l) {
  __builtin_amdgcn_global_load_lds(
      (const __attribute__((address_space(1))) u32*)(const void*)g,
      (__attribute__((address_space(3))) u32*)(void*)l, 16, 0, 0);
}

// ---------------- transpose + cast (fp32 R x C -> bf16 C x R) ----------------
__global__ __launch_bounds__(256) void ktranspose_cast(const float* __restrict__ in,
                                                       u16* __restrict__ out, int R, int C) {
  __shared__ float tile[32][33];
  int tx = threadIdx.x & 31, ty = threadIdx.x >> 5;   // 32 x 8
  int c0 = blockIdx.x * 32, r0 = blockIdx.y * 32;
  #pragma unroll
  for (int i = 0; i < 32; i += 8)
    tile[ty + i][tx] = in[(size_t)(r0 + ty + i) * C + c0 + tx];
  __syncthreads();
  #pragma unroll
  for (int i = 0; i < 32; i += 8)
    out[(size_t)(c0 + ty + i) * R + r0 + tx] = f2b(tile[tx][ty + i]);
}

// ---------- LayerNorm (fp32 in) -> xn (bf16 LN) + xbf (bf16 cast of x) ----------
__global__ __launch_bounds__(256) void lnorm_k(const float* __restrict__ x,
                                               const float* __restrict__ g,
                                               const float* __restrict__ bb,
                                               u16* __restrict__ xn,
                                               u16* __restrict__ xbf) {
  int row = blockIdx.x;
  int t = threadIdx.x;
  float4 rw = *(const float4*)(x + (size_t)row * DIM_ + t * 4);
  float v0 = rw.x, v1 = rw.y, v2 = rw.z, v3 = rw.w;
  uint2 cw;
  cw.x = (unsigned)f2b(v0) | ((unsigned)f2b(v1) << 16);
  cw.y = (unsigned)f2b(v2) | ((unsigned)f2b(v3) << 16);
  *(uint2*)(xbf + (size_t)row * DIM_ + t * 4) = cw;
  float s = v0 + v1 + v2 + v3;
  float ss = v0 * v0 + v1 * v1 + v2 * v2 + v3 * v3;
  #pragma unroll
  for (int o = 32; o; o >>= 1) { s += __shfl_xor(s, o, 64); ss += __shfl_xor(ss, o, 64); }
  __shared__ float red[8];
  int lane = t & 63, w = t >> 6;
  if (lane == 0) { red[w] = s; red[4 + w] = ss; }
  __syncthreads();
  float S = red[0] + red[1] + red[2] + red[3];
  float SS = red[4] + red[5] + red[6] + red[7];
  float mu = S * (1.0f / DIM_);
  float var = SS * (1.0f / DIM_) - mu * mu;
  float rs = rsqrtf(var + 1e-5f);
  float4 gv = *(const float4*)(g + t * 4);
  float4 bv = *(const float4*)(bb + t * 4);
  uint2 ow;
  ow.x = (unsigned)f2b((v0 - mu) * rs * gv.x + bv.x) |
         ((unsigned)f2b((v1 - mu) * rs * gv.y + bv.y) << 16);
  ow.y = (unsigned)f2b((v2 - mu) * rs * gv.z + bv.z) |
         ((unsigned)f2b((v3 - mu) * rs * gv.w + bv.w) << 16);
  *(uint2*)(xn + (size_t)row * DIM_ + t * 4) = ow;
}

// ---------------- MFMA GEMM, tile 128m x 64n, K-step 32, global_load_lds staging ----------
// MODE 1: fp32 row-major -> dst0
// MODE 2: per-row l2norm over 64-col head * scale -> Qn (b,h,n,d)
// MODE 3: cols<1024: l2norm*ks -> Kb (b,h,j=n+2,d) stride JP; cols>=1024: bf16 -> Vb stride J
template <int MODE>
__global__ __launch_bounds__(256, 4) void gemm_k(const u16* __restrict__ A,
                                                 const u16* __restrict__ BT,
                                                 void* __restrict__ dst0,
                                                 void* __restrict__ dst1,
                                                 const float* __restrict__ scale,
                                                 int M, int Nc, int K) {
  __shared__ u16 As[128 * 32];   // unpadded: required by global_load_lds lane mapping
  __shared__ u16 Bs[64 * 32];
  int tid = threadIdx.x, wv = tid >> 6, lane = tid & 63;
  int fm = lane & 15, fg = lane >> 4;
  int row0 = blockIdx.y * 128, col0 = blockIdx.x * 64;
  f32x4 acc[2][4] = {};
  int lr = lane >> 2, lc8 = (lane & 3) * 8;
  const u16* Ag = A + (size_t)(row0 + wv * 32 + lr) * K + lc8;
  const u16* Bg = BT + (size_t)(col0 + wv * 16 + lr) * K + lc8;
  u16* AsW = As + wv * 1024;    // wave wv stages As rows [wv*32, wv*32+32)
  u16* BsW = Bs + wv * 512;     // and Bs rows [wv*16, wv*16+16)
  for (int k0 = 0; k0 < K; k0 += 32) {
    __syncthreads();
    dma16(Ag + k0, AsW);
    dma16(Ag + (size_t)16 * K + k0, AsW + 512);
    dma16(Bg + k0, BsW);
    __syncthreads();
    bf16x8 af0 = *(const bf16x8*)&As[(wv * 32 + fm) * 32 + fg * 8];
    bf16x8 af1 = *(const bf16x8*)&As[(wv * 32 + 16 + fm) * 32 + fg * 8];
    #pragma unroll
    for (int nt = 0; nt < 4; nt++) {
      bf16x8 bfr = *(const bf16x8*)&Bs[(nt * 16 + fm) * 32 + fg * 8];
      acc[0][nt] = __builtin_amdgcn_mfma_f32_16x16x32_bf16(af0, bfr, acc[0][nt], 0, 0, 0);
      acc[1][nt] = __builtin_amdgcn_mfma_f32_16x16x32_bf16(af1, bfr, acc[1][nt], 0, 0, 0);
    }
  }
  if (MODE == 1) {
    float* C = (float*)dst0;
    #pragma unroll
    for (int mt = 0; mt < 2; mt++)
      #pragma unroll
      for (int nt = 0; nt < 4; nt++)
        #pragma unroll
        for (int r = 0; r < 4; r++) {
          int m = row0 + wv * 32 + mt * 16 + fg * 4 + r;
          C[(size_t)m * Nc + col0 + nt * 16 + fm] = acc[mt][nt][r];
        }
  } else {
    bool isK = (MODE == 2) || (col0 < 1024);
    int h = ((MODE == 2) ? col0 : (isK ? col0 : col0 - 1024)) >> 6;
    float sv[4];
    if (isK) {
      #pragma unroll
      for (int nt = 0; nt < 4; nt++) sv[nt] = scale[nt * 16 + fm];
    }
    u16* Do = (u16*)((MODE == 3 && !isK) ? dst1 : dst0);
    #pragma unroll
    for (int mt = 0; mt < 2; mt++) {
      #pragma unroll
      for (int r = 0; r < 4; r++) {
        float inv = 1.0f;
        if (isK) {
          float ssp = 0.0f;
          #pragma unroll
          for (int nt = 0; nt < 4; nt++) ssp += acc[mt][nt][r] * acc[mt][nt][r];
          #pragma unroll
          for (int o = 1; o <= 8; o <<= 1) ssp += __shfl_xor(ssp, o, 64);
          inv = 1.0f / fmaxf(sqrtf(ssp), 1e-12f);
        }
        int m = row0 + wv * 32 + mt * 16 + fg * 4 + r;
        int b = m >> 11, n = m & 2047;
        size_t base;
        if (MODE == 2)      base = (((size_t)(b * H_ + h)) * N_ + n) * 64;
        else if (isK)       base = (((size_t)(b * H_ + h)) * JP_ + (n + NN_)) * 64;
        else                base = (((size_t)(b * H_ + h)) * J_ + (n + NN_)) * 64;
        #pragma unroll
        for (int nt = 0; nt < 4; nt++) {
          float val = acc[mt][nt][r];
          if (isK) val = val * inv * sv[nt];
          Do[base + nt * 16 + fm] = f2b(val);
        }
      }
    }
  }
}

// ------- V transpose+permute: Vb (b,h,j,d) + null kv -> VTp (b,h,d,pos); also Kb j<2 -------
// VTp[bh][d][c*64+pos] = V[bh][c*64 + pi(pos)][d],
// pi(pos): h2=pos>>5, fgp=(pos>>3)&3, nt=(pos>>2)&1, r=pos&3 -> j = (h2*2+nt)*16 + fgp*4 + r
__global__ __launch_bounds__(256) void vtransp_k(const u16* __restrict__ Vb,
                                                 const float* __restrict__ nkv,
                                                 const float* __restrict__ ks,
                                                 u16* __restrict__ Kb,
                                                 u16* __restrict__ VTp) {
  __shared__ u16 tile[64][80];
  int t = threadIdx.x;
  int c = blockIdx.x, bh = blockIdx.y, h = bh & 15;
  int jl = t >> 2, dc = (t & 3) * 16;
  int j = c * 64 + jl;
  if (j < NN_) {
    float kvv[16];
    float kssp = 0.0f;
    #pragma unroll
    for (int e = 0; e < 16; e++) {
      float vv = nkv[(size_t)(h * 4 + 2 * j + 1) * 64 + dc + e];
      tile[jl][dc + e] = f2b(vv);
      float kv = nkv[(size_t)(h * 4 + 2 * j) * 64 + dc + e];
      kvv[e] = kv; kssp += kv * kv;
    }
    kssp += __shfl_xor(kssp, 1, 64);
    kssp += __shfl_xor(kssp, 2, 64);
    float inv = 1.0f / fmaxf(sqrtf(kssp), 1e-12f);
    #pragma unroll
    for (int e = 0; e < 16; e++)
      Kb[((size_t)bh * JP_ + j) * 64 + dc + e] = f2b(kvv[e] * inv * ks[dc + e]);
  } else if (j < J_) {
    const uint4* src = (const uint4*)(Vb + ((size_t)bh * J_ + j) * 64 + dc);
    *(uint4*)&tile[jl][dc] = src[0];
    *(uint4*)&tile[jl][dc + 8] = src[1];
  } else {
    uint4 z = {0, 0, 0, 0};
    *(uint4*)&tile[jl][dc] = z;
    *(uint4*)&tile[jl][dc + 8] = z;
  }
  __syncthreads();
  int d = t >> 2, p0 = (t & 3) * 16;
  u16 tmp[16] __attribute__((aligned(16)));
  #pragma unroll
  for (int e = 0; e < 16; e++) {
    int pos = p0 + e;
    int h2 = pos >> 5, rem = pos & 31;
    int fgp = rem >> 3, tt = rem & 7;
    int nt = tt >> 2, r = tt & 3;
    int jloc = (h2 * 2 + nt) * 16 + fgp * 4 + r;
    tmp[e] = tile[jloc][d];
  }
  uint4* dstp = (uint4*)(VTp + ((size_t)bh * 64 + d) * JP_ + c * 64 + p0);
  dstp[0] = ((uint4*)tmp)[0];
  dstp[1] = ((uint4*)tmp)[1];
}

// ---------------- MFMA flash attention, j-SPLIT partial blocks ----------------
// grid (84 segs x 32 bh); seg decode: qt descending, s(qt)=ceil((qt+2)/8) segments.
// Each block: 64 q-rows (4 waves x 16), <=8 key chunks; fixed-cap softmax (plain sums)
// -> partial O (bf16 [q][d]) + l (fp32 [q]) per slot; combined by comb_k.
__global__ __launch_bounds__(256, 6) void attn_k(const u16* __restrict__ Qn,
                                                 const u16* __restrict__ Kb,
                                                 const u16* __restrict__ VTp,
                                                 const float* __restrict__ qs,
                                                 const float* __restrict__ ks,
                                                 u16* __restrict__ partials) {
  __shared__ u16 Ks0[64 * 32], Ks1[64 * 32];   // K chunk rows j, d 0..31 / 32..63
  __shared__ u16 Vs0[64 * 32], Vs1[64 * 32];   // V^T chunk rows d, j-pos 0..31 / 32..63
  int tid = threadIdx.x;
  int wv = tid >> 6, lane = tid & 63;
  int fm = lane & 15, fg = lane >> 4;
  int bh = blockIdx.y, h = bh & 15;
  // segment decode (qt descending)
  int cum = 0, qt = 0, seg = 0;
  #pragma unroll 1
  for (int i = 0; i < 32; i++) {
    int t = 31 - i, s = (t + 9) >> 3;
    if ((int)blockIdx.x < cum + s) { qt = t; seg = (int)blockIdx.x - cum; break; }
    cum += s;
  }
  int q0 = qt * 64;
  int q = q0 + wv * 16 + fm;
  float slope = exp2f(-0.5f * (float)(h + 1));
  float prod = fabsf(qs[lane] * ks[lane]);
  #pragma unroll
  for (int o = 32; o; o >>= 1) prod = fmaxf(prod, __shfl_xor(prod, o, 64));
  float Mb = 8.0f * prod;
  const u16* qp = Qn + ((size_t)bh * N_ + q) * 64 + fg * 8;
  bf16x8 qf0 = *(const bf16x8*)(qp);        // d 0..31 slice
  bf16x8 qf1 = *(const bf16x8*)(qp + 32);   // d 32..63 slice
  f32x4 accO[4] = {};
  float lp = 0.0f;
  int lr = lane >> 2, lc8 = (lane & 3) * 8;
  const u16* KbBH = Kb + (size_t)bh * JP_ * 64;
  const u16* VTbh = VTp + (size_t)bh * 64 * JP_;
  int c0 = seg * 8;
  int c1 = min(c0 + 8, qt + 2);
  for (int c = c0; c < c1; c++) {
    int jb = c * 64;
    __syncthreads();
    const u16* Kg = KbBH + (size_t)jb * 64 + (size_t)(wv * 16 + lr) * 64 + lc8;
    dma16(Kg,      Ks0 + wv * 512);
    dma16(Kg + 32, Ks1 + wv * 512);
    const u16* Vg = VTbh + (size_t)(wv * 16 + lr) * JP_ + jb + lc8;
    dma16(Vg,      Vs0 + wv * 512);
    dma16(Vg + 32, Vs1 + wv * 512);
    __syncthreads();
    // S^T = K Q^T
    f32x4 accS[4] = {};
    #pragma unroll
    for (int nt = 0; nt < 4; nt++) {
      bf16x8 kf0 = *(const bf16x8*)&Ks0[(nt * 16 + fm) * 32 + fg * 8];
      accS[nt] = __builtin_amdgcn_mfma_f32_16x16x32_bf16(kf0, qf0, accS[nt], 0, 0, 0);
      bf16x8 kf1 = *(const bf16x8*)&Ks1[(nt * 16 + fm) * 32 + fg * 8];
      accS[nt] = __builtin_amdgcn_mfma_f32_16x16x32_bf16(kf1, qf1, accS[nt], 0, 0, 0);
    }
    // softmax in-register; pack P^T B-frags (k-space permutation matches VTp's pi)
    union { bf16x8 v; u16 s[8]; } P0, P1;
    #pragma unroll
    for (int nt = 0; nt < 4; nt++) {
      #pragma unroll
      for (int r = 0; r < 4; r++) {
        int jj = jb + nt * 16 + fg * 4 + r;
        float arg = fmaf(accS[nt][r], 8.0f, slope * (float)(jj - q - 2)) - Mb;
        float p = (jj <= q + 2) ? __expf(arg) : 0.0f;
        u16 pb = f2b(p);
        lp += b2f(pb);
        if (nt < 2) P0.s[nt * 4 + r] = pb;
        else        P1.s[(nt - 2) * 4 + r] = pb;
      }
    }
    // O^T += V^T P^T
    #pragma unroll
    for (int nt = 0; nt < 4; nt++) {
      bf16x8 vf0 = *(const bf16x8*)&Vs0[(nt * 16 + fm) * 32 + fg * 8];
      accO[nt] = __builtin_amdgcn_mfma_f32_16x16x32_bf16(vf0, P0.v, accO[nt], 0, 0, 0);
      bf16x8 vf1 = *(const bf16x8*)&Vs1[(nt * 16 + fm) * 32 + fg * 8];
      accO[nt] = __builtin_amdgcn_mfma_f32_16x16x32_bf16(vf1, P1.v, accO[nt], 0, 0, 0);
    }
  }
  lp += __shfl_xor(lp, 16, 64);
  lp += __shfl_xor(lp, 32, 64);
  // slot: [q 64][d 64] bf16 + l fp32[64]
  u16* P = partials + ((size_t)bh * NSEG_ + blockIdx.x) * 4224;
  int sq = wv * 16 + fm;
  #pragma unroll
  for (int nt = 0; nt < 4; nt++) {
    uint2 ow;
    ow.x = (unsigned)f2b(accO[nt][0]) | ((unsigned)f2b(accO[nt][1]) << 16);
    ow.y = (unsigned)f2b(accO[nt][2]) | ((unsigned)f2b(accO[nt][3]) << 16);
    *(uint2*)(P + sq * 64 + nt * 16 + fg * 4) = ow;
  }
  if (fg == 0) *(float*)(P + 4096 + 2 * sq) = lp;
}

// ---------------- combine partials -> AO (b,n,h,d) ----------------
__global__ __launch_bounds__(256) void comb_k(const u16* __restrict__ partials,
                                              u16* __restrict__ AO) {
  int qt = blockIdx.x, bh = blockIdx.y, b = bh >> 4, h = bh & 15;
  int t = threadIdx.x, q = t >> 2, dq = (t & 3) * 16;
  int s = (qt + 9) >> 3;
  int cum = 0;
  for (int tt = qt + 1; tt < 32; tt++) cum += (tt + 9) >> 3;
  float acc[16] = {};
  float lsum = 0.0f;
  for (int k = 0; k < s; k++) {
    const u16* P = partials + ((size_t)bh * NSEG_ + cum + k) * 4224;
    uint4 a = *(const uint4*)(P + q * 64 + dq);
    uint4 bq = *(const uint4*)(P + q * 64 + dq + 8);
    float tmp[8];
    unp8(a, tmp);
    #pragma unroll
    for (int e = 0; e < 8; e++) acc[e] += tmp[e];
    unp8(bq, tmp);
    #pragma unroll
    for (int e = 0; e < 8; e++) acc[8 + e] += tmp[e];
    lsum += *(const float*)(P + 4096 + 2 * q);
  }
  float linv = 1.0f / lsum;
  int n = qt * 64 + q;
  u16* dst = AO + (((size_t)(b * N_ + n)) * H_ + h) * 64 + dq;
  u16 ov[16] __attribute__((aligned(16)));
  #pragma unroll
  for (int e = 0; e < 16; e++) ov[e] = f2b(acc[e] * linv);
  *(uint4*)dst = ((uint4*)ov)[0];
  *(uint4*)(dst + 8) = ((uint4*)ov)[1];
}

// ---------------- launch ----------------
extern "C" void kernel_launch(void* const* d_in, const int* in_sizes, int n_in,
                              void* d_out, int out_size, void* d_ws, size_t ws_size,
                              hipStream_t stream) {
  const float* x    = (const float*)d_in[0];
  const float* ng   = (const float*)d_in[1];
  const float* nb   = (const float*)d_in[2];
  const float* Wq   = (const float*)d_in[3];
  const float* Wkv  = (const float*)d_in[4];
  const float* qs   = (const float*)d_in[5];
  const float* ks   = (const float*)d_in[6];
  const float* nkv  = (const float*)d_in[7];
  const float* Wout = (const float*)d_in[8];
  float* out = (float*)d_out;
  char* ws = (char*)d_ws;

  // layout (bytes):
  u16* xn    = (u16*)(ws + 0);            // 8,388,608 (AO reuses after Q-GEMM)
  u16* WoutT = (u16*)(ws + 8388608);      // 2,097,152
  u16* Qn    = (u16*)(ws + 10485760);     // 8,388,608
  u16* Kb    = (u16*)(ws + 18874368);     // 8,650,752 (JP stride)
  u16* VTp   = (u16*)(ws + 27525120);     // 8,650,752
  // overlay region @36175872 (dead by attn time):
  u16* xbf   = (u16*)(ws + 36175872);     // 8,388,608  (dead after KV-GEMM)
  u16* WqT   = (u16*)(ws + 44564480);     // 2,097,152  (dead after Q-GEMM)
  u16* WkvT  = (u16*)(ws + 46661632);     // 4,194,304  (dead after KV-GEMM)
  u16* Vb    = (u16*)(ws + 50855936);     // 8,396,800  (dead after vtransp) end 59,252,736
  u16* parts = xbf;                       // 32*84*8448 = 22,708,224 (fits overlay)
  u16* AO    = xn;

  hipMemsetAsync(Kb, 0, 8650752, stream);   // zero JP tail rows (graph-capturable)
  ktranspose_cast<<<dim3(32, 32), 256, 0, stream>>>(Wq, WqT, 1024, 1024);
  ktranspose_cast<<<dim3(64, 32), 256, 0, stream>>>(Wkv, WkvT, 1024, 2048);
  ktranspose_cast<<<dim3(32, 32), 256, 0, stream>>>(Wout, WoutT, 1024, 1024);
  lnorm_k<<<4096, 256, 0, stream>>>(x, ng, nb, xn, xbf);
  gemm_k<2><<<dim3(16, 32), 256, 0, stream>>>(xn, WqT, Qn, nullptr, qs, M_, 1024, 1024);
  gemm_k<3><<<dim3(32, 32), 256, 0, stream>>>(xbf, WkvT, Kb, Vb, ks, M_, 2048, 1024);
  vtransp_k<<<dim3(33, 32), 256, 0, stream>>>(Vb, nkv, ks, Kb, VTp);
  attn_k<<<dim3(NSEG_, 32), 256, 0, stream>>>(Qn, Kb, VTp, qs, ks, parts);
  comb_k<<<dim3(32, 32), 256, 0, stream>>>(parts, AO);
  gemm_k<1><<<dim3(16, 32), 256, 0, stream>>>(AO, WoutT, out, nullptr, nullptr, M_, 1024, 1024);
}